// Round 1
// baseline (42.523 us; speedup 1.0000x reference)
//
#include <hip/hip_runtime.h>
#include <stdint.h>

#define NW 169   // 13*13 windows

__device__ __forceinline__ float qw128(float x) {
    // fake_quant(w, 128, 8): clip(round(w*128), -128, 127)/128   (round = half-to-even)
    float r = rintf(x * 128.f);
    r = fminf(fmaxf(r, -128.f), 127.f);
    return r * 0.0078125f;
}
__device__ __forceinline__ float qb16384(float x) {
    // fake_quant(b, 128*128, 32): round(b*16384)/16384 (int32 clamp unreachable here)
    return rintf(x * 16384.f) * 6.103515625e-05f;
}

// Pre-quantize embedding table to biased uint8: q = clip(round(clip(x,-1,127/128)*128),-128,127)+128
__global__ void quant_emb_kernel(const float* __restrict__ emb, uint8_t* __restrict__ q) {
    int i = blockIdx.x * 256 + threadIdx.x;             // 16 floats per thread, 2048 blocks
    const float4* in4 = (const float4*)emb + (size_t)i * 4;
    uint32_t words[4];
#pragma unroll
    for (int t = 0; t < 4; ++t) {
        float4 f = in4[t];
        float v[4] = {f.x, f.y, f.z, f.w};
        uint32_t w = 0;
#pragma unroll
        for (int j = 0; j < 4; ++j) {
            float x = fminf(fmaxf(v[j], -1.f), 0.9921875f);
            int r = (int)rintf(x * 128.f) + 128;        // [0,255]
            w |= ((uint32_t)r & 0xFFu) << (8 * j);
        }
        words[t] = w;
    }
    ((uint4*)q)[i] = make_uint4(words[0], words[1], words[2], words[3]);
}

// policy output is all zeros; d_out is poisoned before timing so rewrite every call
__global__ void zero_policy_kernel(float4* __restrict__ p) {
    int i = blockIdx.x * 256 + threadIdx.x;             // 460800 float4 total, 1800 blocks
    p[i] = make_float4(0.f, 0.f, 0.f, 0.f);
}

__global__ void nnue_kernel(const int* __restrict__ board,
                            const uint8_t* __restrict__ embq,
                            const float* __restrict__ w1, const float* __restrict__ b1,
                            const float* __restrict__ w2, const float* __restrict__ b2,
                            const float* __restrict__ w3, const float* __restrict__ b3,
                            float* __restrict__ vout)
{
    __shared__ float w1T[32][32], w2T[32][32], w3T[32][4];   // transposed: [k][j], conflict-free reads
    __shared__ float b1q[32], b2q[32], b3q[4];
    __shared__ unsigned long long ballots[4][8];             // per-wave 512-bit board bitmap
    __shared__ int hashoff[4][176];                          // idx<<5 per window
    __shared__ float vlds[4][32], h1lds[4][32], h2lds[4][32];

    int tid = threadIdx.x;
    // stage quantized weights (amortized over 4 boards/block; hot in L2 anyway)
    for (int i = tid; i < 1024; i += 256) {
        int j = i & 31, k = i >> 5;
        w1T[k][j] = qw128(w1[j * 32 + k]);
        w2T[k][j] = qw128(w2[j * 32 + k]);
    }
    if (tid < 96) { int k = tid & 31, j = tid >> 5; w3T[k][j] = qw128(w3[j * 32 + k]); }
    if (tid < 32) { b1q[tid] = qb16384(b1[tid]); b2q[tid] = qb16384(b2[tid]); }
    if (tid < 3)  b3q[tid] = qb16384(b3[tid]);

    int wv = tid >> 6, lane = tid & 63;
    int b = blockIdx.x * 4 + wv;                         // grid 2048 * 4 waves = 8192 boards
    const int* bp = board + b * 450;

    // phase 1: pack 450 cells into 8x u64 via ballot (coalesced dword loads)
#pragma unroll
    for (int t = 0; t < 8; ++t) {
        int n = t * 64 + lane;
        int cell = (n < 450) ? bp[n] : 0;
        unsigned long long m = __ballot(cell != 0);
        if (lane == 0) ballots[wv][t] = m;
    }
    __syncthreads();

    // phase 2: 169 window hashes; bit f=9c+3i+j of idx = cell(c, wi+i, wj+j)
#pragma unroll
    for (int t = 0; t < 3; ++t) {
        int w = t * 64 + lane;
        if (w < NW) {
            int wi = w / 13;
            int wj = w - wi * 13;
            int idx = 0;
#pragma unroll
            for (int c = 0; c < 2; ++c) {
#pragma unroll
                for (int i = 0; i < 3; ++i) {
                    int s = c * 225 + (wi + i) * 15;     // bit start of row (c, wi+i)
                    int word = s >> 6, off = s & 63;
                    unsigned long long lo = ballots[wv][word];
                    unsigned long long hi = ballots[wv][word + 1];
                    // (lo>>off)|(hi<<(64-off)); double-shift avoids UB and yields 0 at off==0
                    unsigned long long bits = (lo >> off) | ((hi << 1) << (63 - off));
                    idx |= (int)((bits >> wj) & 7ull) << (9 * c + 3 * i);
                }
            }
            hashoff[wv][w] = idx << 5;                   // byte offset of row
        }
    }
    __syncthreads();

    // phase 3: gather-accumulate. group g = lane>>2 handles windows g, g+16, ...
    // lane loads bytes [d2*8, d2*8+8) of the row -> channels 8*d2 .. 8*d2+7
    int d2 = lane & 3;
    int g = lane >> 2;
    const uint8_t* base = embq + d2 * 8;
    uint32_t a02lo = 0, a13lo = 0, a02hi = 0, a13hi = 0;  // packed u16 pairs, biased by +128/window
#pragma unroll
    for (int it = 0; it < 11; ++it) {
        int w = it * 16 + g;
        if (w < NW) {
            int off = hashoff[wv][w];
            uint2 dw = *(const uint2*)(base + off);
            a02lo += dw.x & 0x00FF00FFu;
            a13lo += (dw.x >> 8) & 0x00FF00FFu;
            a02hi += dw.y & 0x00FF00FFu;
            a13hi += (dw.y >> 8) & 0x00FF00FFu;
        }
    }
    // reduce across 16 groups; max per u16 half = 169*255 = 43095 < 65536, no carry
#pragma unroll
    for (int off = 4; off <= 32; off <<= 1) {
        a02lo += __shfl_xor(a02lo, off);
        a13lo += __shfl_xor(a13lo, off);
        a02hi += __shfl_xor(a02hi, off);
        a13hi += __shfl_xor(a13hi, off);
    }
    if (lane < 4) {                                      // lane == d2 here
        int c[8];
        c[0] = (int)(a02lo & 0xFFFFu) - 21632;           // 128*169 bias
        c[2] = (int)(a02lo >> 16)     - 21632;
        c[1] = (int)(a13lo & 0xFFFFu) - 21632;
        c[3] = (int)(a13lo >> 16)     - 21632;
        c[4] = (int)(a02hi & 0xFFFFu) - 21632;
        c[6] = (int)(a02hi >> 16)     - 21632;
        c[5] = (int)(a13hi & 0xFFFFu) - 21632;
        c[7] = (int)(a13hi >> 16)     - 21632;
#pragma unroll
        for (int j = 0; j < 8; ++j) {
            int cc = min(max(c[j], -128), 127);          // clip(v,-1,127/128) exactly
            vlds[wv][lane * 8 + j] = (float)cc * 0.0078125f;
        }
    }
    __syncthreads();

    // MLP: lane jj in [0,32) computes output jj; halves split k and combine via shfl_xor(32)
    int jj = lane & 31, hf = lane >> 5;
    float s1 = 0.f;
#pragma unroll
    for (int k2 = 0; k2 < 16; ++k2) {
        int k = hf * 16 + k2;
        s1 = fmaf(vlds[wv][k], w1T[k][jj], s1);
    }
    s1 += __shfl_xor(s1, 32);
    s1 += b1q[jj];
    s1 = fminf(fmaxf(s1, 0.f), 0.9921875f);
    if (lane < 32) h1lds[wv][jj] = s1;
    __syncthreads();

    float s2 = 0.f;
#pragma unroll
    for (int k2 = 0; k2 < 16; ++k2) {
        int k = hf * 16 + k2;
        s2 = fmaf(h1lds[wv][k], w2T[k][jj], s2);
    }
    s2 += __shfl_xor(s2, 32);
    s2 += b2q[jj];
    s2 = fminf(fmaxf(s2, 0.f), 0.9921875f);
    if (lane < 32) h2lds[wv][jj] = s2;
    __syncthreads();

    float s3 = 0.f;
    if (jj < 3) {
#pragma unroll
        for (int k2 = 0; k2 < 16; ++k2) {
            int k = hf * 16 + k2;
            s3 = fmaf(h2lds[wv][k], w3T[k][jj], s3);
        }
    }
    s3 += __shfl_xor(s3, 32);
    if (lane < 3) vout[b * 3 + lane] = s3 + b3q[lane];
}

extern "C" void kernel_launch(void* const* d_in, const int* in_sizes, int n_in,
                              void* d_out, int out_size, void* d_ws, size_t ws_size,
                              hipStream_t stream) {
    const int*   board = (const int*)d_in[0];
    const float* emb   = (const float*)d_in[1];
    const float* w1    = (const float*)d_in[2];
    const float* b1    = (const float*)d_in[3];
    const float* w2    = (const float*)d_in[4];
    const float* b2    = (const float*)d_in[5];
    const float* w3    = (const float*)d_in[6];
    const float* b3    = (const float*)d_in[7];
    float* out = (float*)d_out;
    uint8_t* embq = (uint8_t*)d_ws;                      // 2^18 * 32 = 8.4 MB

    // v = out[0 : 8192*3], policy = out[24576 : 24576+1843200]
    quant_emb_kernel<<<2048, 256, 0, stream>>>(emb, embq);
    zero_policy_kernel<<<1800, 256, 0, stream>>>((float4*)(out + 24576));
    nnue_kernel<<<2048, 256, 0, stream>>>(board, embq, w1, b1, w2, b2, w3, b3, out);
}

// Round 2
// 37.103 us; speedup vs baseline: 1.1461x; 1.1461x over previous
//
#include <hip/hip_runtime.h>
#include <stdint.h>

#define NW 169   // 13*13 windows

__device__ __forceinline__ float qw128(float x) {
    // fake_quant(w, 128, 8): clip(round(w*128), -128, 127)/128   (round = half-to-even)
    float r = rintf(x * 128.f);
    r = fminf(fmaxf(r, -128.f), 127.f);
    return r * 0.0078125f;
}
__device__ __forceinline__ float qb16384(float x) {
    // fake_quant(b, 128*128, 32): round(b*16384)/16384 (int32 clamp unreachable here)
    return rintf(x * 16384.f) * 6.103515625e-05f;
}

// Fused: blocks [0,2048) quantize the 2^18 x 32 embedding table to biased uint8;
// blocks [2048,3848) zero the policy plane (d_out poisoned before timing).
__global__ void prep_kernel(const float* __restrict__ emb, uint8_t* __restrict__ q,
                            float4* __restrict__ policy) {
    int bid = blockIdx.x;
    int tid = threadIdx.x;
    if (bid >= 2048) {
        int i = (bid - 2048) * 256 + tid;               // 460800 float4 total
        policy[i] = make_float4(0.f, 0.f, 0.f, 0.f);
        return;
    }
    int i = bid * 256 + tid;                            // 16 floats per thread
    const float4* in4 = (const float4*)emb + (size_t)i * 4;
    uint32_t words[4];
#pragma unroll
    for (int t = 0; t < 4; ++t) {
        float4 f = in4[t];
        float v[4] = {f.x, f.y, f.z, f.w};
        uint32_t w = 0;
#pragma unroll
        for (int j = 0; j < 4; ++j) {
            float x = fminf(fmaxf(v[j], -1.f), 0.9921875f);
            int r = (int)rintf(x * 128.f) + 128;        // [0,255]
            w |= ((uint32_t)r & 0xFFu) << (8 * j);
        }
        words[t] = w;
    }
    ((uint4*)q)[i] = make_uint4(words[0], words[1], words[2], words[3]);
}

__global__ __launch_bounds__(512, 1)
void nnue_kernel(const int* __restrict__ board,
                 const uint8_t* __restrict__ embq,
                 const float* __restrict__ w1, const float* __restrict__ b1,
                 const float* __restrict__ w2, const float* __restrict__ b2,
                 const float* __restrict__ w3, const float* __restrict__ b3,
                 float* __restrict__ vout)
{
    __shared__ float w1T[32][32], w2T[32][32], w3T[32][4];   // transposed: [k][j]
    __shared__ float b1q[32], b2q[32], b3q[4];
    // Everything below is WAVE-PRIVATE (indexed by wv, produced+consumed by the
    // same wave) -> no __syncthreads needed after the weight-staging barrier;
    // intra-wave LDS RAW is ordered by lgkmcnt which the compiler inserts.
    __shared__ unsigned long long ballots[8][8];             // per-wave 512-bit board bitmap
    __shared__ int hashoff[8][176];                          // idx<<5 per window
    __shared__ float vlds[8][32], h1lds[8][32], h2lds[8][32];

    int tid = threadIdx.x;
    // stage quantized weights (amortized over 8 boards/block; w1/w2 hot in L2)
    for (int i = tid; i < 1024; i += 512) {
        int j = i & 31, k = i >> 5;
        w1T[k][j] = qw128(w1[j * 32 + k]);
        w2T[k][j] = qw128(w2[j * 32 + k]);
    }
    if (tid < 96) { int k = tid & 31, j = tid >> 5; w3T[k][j] = qw128(w3[j * 32 + k]); }
    if (tid < 32) { b1q[tid] = qb16384(b1[tid]); b2q[tid] = qb16384(b2[tid]); }
    if (tid < 3)  b3q[tid] = qb16384(b3[tid]);
    __syncthreads();                                     // ONLY block-wide barrier

    int wv = tid >> 6, lane = tid & 63;
    int b = blockIdx.x * 8 + wv;                         // grid 1024 * 8 waves = 8192 boards
    const int* bp = board + b * 450;

    // phase 1: pack 450 cells into 8x u64 via ballot (coalesced dword loads)
#pragma unroll
    for (int t = 0; t < 8; ++t) {
        int n = t * 64 + lane;
        int cell = (n < 450) ? bp[n] : 0;
        unsigned long long m = __ballot(cell != 0);
        if (lane == 0) ballots[wv][t] = m;
    }

    // phase 2: 169 window hashes; bit f=9c+3i+j of idx = cell(c, wi+i, wj+j)
#pragma unroll
    for (int t = 0; t < 3; ++t) {
        int w = t * 64 + lane;
        if (w < NW) {
            int wi = w / 13;
            int wj = w - wi * 13;
            int idx = 0;
#pragma unroll
            for (int c = 0; c < 2; ++c) {
#pragma unroll
                for (int i = 0; i < 3; ++i) {
                    int s = c * 225 + (wi + i) * 15;     // bit start of row (c, wi+i)
                    int word = s >> 6, off = s & 63;
                    unsigned long long lo = ballots[wv][word];
                    unsigned long long hi = ballots[wv][word + 1];
                    // (lo>>off)|(hi<<(64-off)); double-shift avoids UB, 0 at off==0
                    unsigned long long bits = (lo >> off) | ((hi << 1) << (63 - off));
                    idx |= (int)((bits >> wj) & 7ull) << (9 * c + 3 * i);
                }
            }
            hashoff[wv][w] = idx << 5;                   // byte offset of row
        }
    }

    // phase 3: gather-accumulate. group g = lane>>2 handles windows g, g+16, ...
    // lane loads bytes [d2*8, d2*8+8) of the row -> channels 8*d2 .. 8*d2+7
    int d2 = lane & 3;
    int g = lane >> 2;
    const uint8_t* base = embq + d2 * 8;
    uint32_t a02lo = 0, a13lo = 0, a02hi = 0, a13hi = 0;  // packed u16 pairs, +128/window bias
#pragma unroll
    for (int it = 0; it < 11; ++it) {
        int w = it * 16 + g;
        if (w < NW) {
            int off = hashoff[wv][w];
            uint2 dw = *(const uint2*)(base + off);
            a02lo += dw.x & 0x00FF00FFu;
            a13lo += (dw.x >> 8) & 0x00FF00FFu;
            a02hi += dw.y & 0x00FF00FFu;
            a13hi += (dw.y >> 8) & 0x00FF00FFu;
        }
    }
    // reduce across 16 groups; max per u16 half = 169*255 = 43095 < 65536, no carry
#pragma unroll
    for (int off = 4; off <= 32; off <<= 1) {
        a02lo += __shfl_xor(a02lo, off);
        a13lo += __shfl_xor(a13lo, off);
        a02hi += __shfl_xor(a02hi, off);
        a13hi += __shfl_xor(a13hi, off);
    }
    if (lane < 4) {                                      // lane == d2 here
        int c[8];
        c[0] = (int)(a02lo & 0xFFFFu) - 21632;           // 128*169 bias
        c[2] = (int)(a02lo >> 16)     - 21632;
        c[1] = (int)(a13lo & 0xFFFFu) - 21632;
        c[3] = (int)(a13lo >> 16)     - 21632;
        c[4] = (int)(a02hi & 0xFFFFu) - 21632;
        c[6] = (int)(a02hi >> 16)     - 21632;
        c[5] = (int)(a13hi & 0xFFFFu) - 21632;
        c[7] = (int)(a13hi >> 16)     - 21632;
#pragma unroll
        for (int j = 0; j < 8; ++j) {
            int cc = min(max(c[j], -128), 127);          // clip(v,-1,127/128) exactly
            vlds[wv][lane * 8 + j] = (float)cc * 0.0078125f;
        }
    }

    // MLP: lane jj in [0,32) computes output jj; halves split k, combine via shfl_xor(32)
    int jj = lane & 31, hf = lane >> 5;
    float s1 = 0.f;
#pragma unroll
    for (int k2 = 0; k2 < 16; ++k2) {
        int k = hf * 16 + k2;
        s1 = fmaf(vlds[wv][k], w1T[k][jj], s1);
    }
    s1 += __shfl_xor(s1, 32);
    s1 += b1q[jj];
    s1 = fminf(fmaxf(s1, 0.f), 0.9921875f);
    if (lane < 32) h1lds[wv][jj] = s1;

    float s2 = 0.f;
#pragma unroll
    for (int k2 = 0; k2 < 16; ++k2) {
        int k = hf * 16 + k2;
        s2 = fmaf(h1lds[wv][k], w2T[k][jj], s2);
    }
    s2 += __shfl_xor(s2, 32);
    s2 += b2q[jj];
    s2 = fminf(fmaxf(s2, 0.f), 0.9921875f);
    if (lane < 32) h2lds[wv][jj] = s2;

    float s3 = 0.f;
    if (jj < 3) {
#pragma unroll
        for (int k2 = 0; k2 < 16; ++k2) {
            int k = hf * 16 + k2;
            s3 = fmaf(h2lds[wv][k], w3T[k][jj], s3);
        }
    }
    s3 += __shfl_xor(s3, 32);
    if (lane < 3) vout[b * 3 + lane] = s3 + b3q[lane];
}

extern "C" void kernel_launch(void* const* d_in, const int* in_sizes, int n_in,
                              void* d_out, int out_size, void* d_ws, size_t ws_size,
                              hipStream_t stream) {
    const int*   board = (const int*)d_in[0];
    const float* emb   = (const float*)d_in[1];
    const float* w1    = (const float*)d_in[2];
    const float* b1    = (const float*)d_in[3];
    const float* w2    = (const float*)d_in[4];
    const float* b2    = (const float*)d_in[5];
    const float* w3    = (const float*)d_in[6];
    const float* b3    = (const float*)d_in[7];
    float* out = (float*)d_out;
    uint8_t* embq = (uint8_t*)d_ws;                      // 2^18 * 32 = 8.4 MB

    // v = out[0 : 8192*3], policy = out[24576 : 24576+1843200]
    prep_kernel<<<3848, 256, 0, stream>>>(emb, embq, (float4*)(out + 24576));
    nnue_kernel<<<1024, 512, 0, stream>>>(board, embq, w1, b1, w2, b2, w3, b3, out);
}